// Round 1
// baseline (1615.030 us; speedup 1.0000x reference)
//
#include <hip/hip_runtime.h>
#include <math.h>

#define Bn 64
#define Sn 512
#define Zn 1024
#define H1n 512
#define H2n 256
#define ZSn (Zn*Sn)

// workspace float offsets
#define OFF_LP1  0          // 1024
#define OFF_VML  1024       // 64*256
#define OFF_U    17408      // 64*1024
#define OFF_V    82944      // 64*512
#define OFF_R    115712     // 64*1024
#define OFF_W    181248     // 64*512
#define OFF_RES  214016     // 64*1024
#define OFF_PM   279552     // 64*8*512
#define OFF_PS   541696     // 64*8*512
// total 803840 floats ~= 3.07 MB

__device__ __forceinline__ float wred_max(float x){
#pragma unroll
  for (int o=32;o;o>>=1) x = fmaxf(x, __shfl_xor(x, o, 64));
  return x;
}
__device__ __forceinline__ float wred_sum(float x){
#pragma unroll
  for (int o=32;o;o>>=1) x += __shfl_xor(x, o, 64);
  return x;
}
__device__ __forceinline__ float lae(float a, float c){
  // logaddexp, c may be -inf
  float m = fmaxf(a,c), n = fminf(a,c);
  return m + log1pf(__expf(n-m));
}

// blocks 0..63: zero v-potential; block 64: lp1 = log_softmax(prior)
__global__ __launch_bounds__(512) void prep_kernel(const float* __restrict__ prior,
                                                   float* __restrict__ ws){
  int b = blockIdx.x, t = threadIdx.x;
  if (b < Bn){ ws[OFF_V + b*Sn + t] = 0.f; return; }
  __shared__ float red[8];
  float x0 = prior[t], x1 = prior[t+512];
  float m = wred_max(fmaxf(x0,x1));
  if ((t&63)==0) red[t>>6] = m;
  __syncthreads();
  float M = red[0];
#pragma unroll
  for (int i=1;i<8;i++) M = fmaxf(M, red[i]);
  float e = __expf(x0-M)+__expf(x1-M);
  e = wred_sum(e);
  __syncthreads();
  if ((t&63)==0) red[t>>6] = e;
  __syncthreads();
  float T = 0.f;
#pragma unroll
  for (int i=0;i<8;i++) T += red[i];
  float lse = M + logf(T);
  ws[OFF_LP1 + t]       = x0 - lse;
  ws[OFF_LP1 + t + 512] = x1 - lse;
}

// one block per batch: softmax -> sigmoid MLP -> V[b][0..255]
__global__ __launch_bounds__(512) void mlp_kernel(const float* __restrict__ sl,
    const float* __restrict__ W1, const float* __restrict__ b1,
    const float* __restrict__ W2, const float* __restrict__ b2,
    float* __restrict__ ws){
  __shared__ float p[Sn];
  __shared__ float h1s[H1n];
  __shared__ float red[8];
  int b = blockIdx.x, t = threadIdx.x;
  float x = sl[b*Sn + t];
  float m = wred_max(x);
  if ((t&63)==0) red[t>>6] = m;
  __syncthreads();
  float M = red[0];
#pragma unroll
  for (int i=1;i<8;i++) M = fmaxf(M, red[i]);
  float e = __expf(x-M);
  float es = wred_sum(e);
  __syncthreads();
  if ((t&63)==0) red[t>>6] = es;
  __syncthreads();
  float T = 0.f;
#pragma unroll
  for (int i=0;i<8;i++) T += red[i];
  p[t] = e / T;
  __syncthreads();
  float acc = b1[t];
#pragma unroll 8
  for (int s=0;s<Sn;s++) acc = fmaf(p[s], W1[s*H1n + t], acc);
  h1s[t] = 1.f/(1.f+__expf(-acc));
  __syncthreads();
  if (t < H2n){
    float a2 = b2[t];
#pragma unroll 8
    for (int s=0;s<H1n;s++) a2 = fmaf(h1s[s], W2[s*H2n + t], a2);
    ws[OFF_VML + b*H2n + t] = 1.f/(1.f+__expf(-a2));
  }
}

// K[b,zs] = sum_h V[b][h]*Wout[h,zs] + bout[zs]; K lives in d_out.
// Each thread: 2 zs, 64 batch accumulators. V reads are wave-uniform -> s_load.
__global__ __launch_bounds__(256,2) void gemm_kernel(const float* __restrict__ Wout,
    const float* __restrict__ bout, const float* __restrict__ ws, float* __restrict__ K){
  int zh = blockIdx.x*256 + threadIdx.x;     // float2 index into zs
  const float* V = ws + OFF_VML;
  float2 acc[Bn];
#pragma unroll
  for (int b=0;b<Bn;b++){ acc[b].x = 0.f; acc[b].y = 0.f; }
  const float2* Wp = (const float2*)Wout;
  for (int h=0; h<H2n; h++){
    float2 wv = Wp[(size_t)h*(ZSn/2) + zh];
#pragma unroll
    for (int b=0;b<Bn;b++){
      float vb = V[b*H2n + h];
      acc[b].x = fmaf(vb, wv.x, acc[b].x);
      acc[b].y = fmaf(vb, wv.y, acc[b].y);
    }
  }
  float2 bb = ((const float2*)bout)[zh];
#pragma unroll
  for (int b=0;b<Bn;b++){
    float2 o; o.x = acc[b].x + bb.x; o.y = acc[b].y + bb.y;
    ((float2*)(K + (size_t)b*ZSn))[zh] = o;
  }
}

// one wave per row (b,z): L = LSE_s(K[row,:] + vec[b,:])
// mode 0: u = lp1 - L   mode 1: r = L, u = lp1 - L   mode 2: resample from L - r
__global__ __launch_bounds__(256) void row_pass(const float* __restrict__ K,
    float* __restrict__ ws, int vecoff, int mode){
  int row = blockIdx.x*4 + (threadIdx.x>>6);
  int l = threadIdx.x & 63;
  int b = row >> 10, z = row & (Zn-1);
  const float4* Kr = (const float4*)(K + (size_t)row*Sn);
  const float4* Vr = (const float4*)(ws + vecoff + b*Sn);
  float4 k0 = Kr[l], k1 = Kr[l+64];
  float4 v0 = Vr[l], v1 = Vr[l+64];
  float x0=k0.x+v0.x, x1=k0.y+v0.y, x2=k0.z+v0.z, x3=k0.w+v0.w;
  float x4=k1.x+v1.x, x5=k1.y+v1.y, x6=k1.z+v1.z, x7=k1.w+v1.w;
  float m = fmaxf(fmaxf(fmaxf(x0,x1),fmaxf(x2,x3)), fmaxf(fmaxf(x4,x5),fmaxf(x6,x7)));
  m = wred_max(m);
  float s = __expf(x0-m)+__expf(x1-m)+__expf(x2-m)+__expf(x3-m)
          + __expf(x4-m)+__expf(x5-m)+__expf(x6-m)+__expf(x7-m);
  s = wred_sum(s);
  if (l==0){
    float L = m + logf(s);
    if (mode==0){
      ws[OFF_U + row] = ws[OFF_LP1 + z] - L;
    } else if (mode==1){
      ws[OFF_R + row] = L;
      ws[OFF_U + row] = ws[OFF_LP1 + z] - L;
    } else {
      float lk = L - ws[OFF_R + row];
      ws[OFF_RES + row] = (lk >= 0.f) ? -__builtin_inff() : log1pf(-__expf(lk));
    }
  }
}

// partial column LSE over a 128-row chunk: online (m,sum) per (b,zc,s)
__global__ __launch_bounds__(512) void col_pass1(const float* __restrict__ K,
                                                 float* __restrict__ ws){
  int bzc = blockIdx.x; int b = bzc >> 3, zc = bzc & 7, s = threadIdx.x;
  const float* Kb = K + (size_t)b*ZSn + (size_t)zc*128*Sn;
  const float* ub = ws + OFF_U + b*Zn + zc*128;
  float m = -__builtin_inff(), sum = 0.f;
#pragma unroll 4
  for (int i=0;i<128;i++){
    float x = Kb[i*Sn + s] + ub[i];
    float nm = fmaxf(m, x);
    sum = sum*__expf(m-nm) + __expf(x-nm);
    m = nm;
  }
  ws[OFF_PM + bzc*Sn + s] = m;
  ws[OFF_PS + bzc*Sn + s] = sum;
}

// combine 8 partials -> L = LSE_z(K+u).  modeB=0: v = lp2 - L
// modeB=1: accept_raw = lp2 - v - L; w = v + accept_raw - max_s(accept_raw)
__global__ __launch_bounds__(512) void col_pass2(float* __restrict__ ws,
    const float* __restrict__ sl, int modeB){
  int b = blockIdx.x, s = threadIdx.x;
  float M = -__builtin_inff(), T = 0.f;
#pragma unroll
  for (int zc=0;zc<8;zc++){
    float m = ws[OFF_PM + (b*8+zc)*Sn + s];
    float t = ws[OFF_PS + (b*8+zc)*Sn + s];
    float nM = fmaxf(M, m);
    T = T*__expf(M-nM) + t*__expf(m-nM);
    M = nM;
  }
  float L = M + logf(T);
  float lp2 = sl[b*Sn + s];
  if (!modeB){
    ws[OFF_V + b*Sn + s] = lp2 - L;
  } else {
    __shared__ float red[8];
    float vv = ws[OFF_V + b*Sn + s];
    float araw = lp2 - vv - L;
    float mm = wred_max(araw);
    if ((s&63)==0) red[s>>6] = mm;
    __syncthreads();
    float amax = red[0];
#pragma unroll
    for (int i=1;i<8;i++) amax = fmaxf(amax, red[i]);
    ws[OFF_W + b*Sn + s] = vv + araw - amax;
  }
}

// out = lp1[z] + logaddexp(K - r[row] + w[b,s], resample[row] + lp2[b,s])  (in-place on K)
__global__ __launch_bounds__(256) void final_kernel(float* __restrict__ K,
    const float* __restrict__ ws, const float* __restrict__ sl){
  int idx4 = blockIdx.x*256 + threadIdx.x;     // float4 index
  int row = idx4 >> 7;
  int c4  = idx4 & 127;
  int b = row >> 10, z = row & (Zn-1);
  float r  = ws[OFF_R + row];
  float rs = ws[OFF_RES + row];
  float l1 = ws[OFF_LP1 + z];
  float4 k = ((const float4*)K)[idx4];
  float4 w = ((const float4*)(ws + OFF_W + b*Sn))[c4];
  float4 p = ((const float4*)(sl + (size_t)b*Sn))[c4];
  float4 o;
  o.x = l1 + lae(k.x - r + w.x, rs + p.x);
  o.y = l1 + lae(k.y - r + w.y, rs + p.y);
  o.z = l1 + lae(k.z - r + w.z, rs + p.z);
  o.w = l1 + lae(k.w - r + w.w, rs + p.w);
  ((float4*)K)[idx4] = o;
}

extern "C" void kernel_launch(void* const* d_in, const int* in_sizes, int n_in,
                              void* d_out, int out_size, void* d_ws, size_t ws_size,
                              hipStream_t stream) {
  const float* sl    = (const float*)d_in[0];
  const float* W1    = (const float*)d_in[1];
  const float* b1    = (const float*)d_in[2];
  const float* W2    = (const float*)d_in[3];
  const float* b2    = (const float*)d_in[4];
  const float* Wout  = (const float*)d_in[5];
  const float* bout  = (const float*)d_in[6];
  const float* prior = (const float*)d_in[7];
  float* K  = (float*)d_out;          // K lives in d_out; transformed in place at end
  float* ws = (float*)d_ws;

  prep_kernel<<<Bn+1, 512, 0, stream>>>(prior, ws);
  mlp_kernel<<<Bn, 512, 0, stream>>>(sl, W1, b1, W2, b2, ws);
  gemm_kernel<<<ZSn/512, 256, 0, stream>>>(Wout, bout, ws, K);

  for (int it = 0; it < 10; ++it){
    row_pass <<<Bn*Zn/4, 256, 0, stream>>>(K, ws, OFF_V, 0);
    col_pass1<<<Bn*8,    512, 0, stream>>>(K, ws);
    col_pass2<<<Bn,      512, 0, stream>>>(ws, sl, 0);
  }
  // rejection: r-pass (row), c-pass (col, modeB -> w), t-pass (row -> resample)
  row_pass <<<Bn*Zn/4, 256, 0, stream>>>(K, ws, OFF_V, 1);
  col_pass1<<<Bn*8,    512, 0, stream>>>(K, ws);
  col_pass2<<<Bn,      512, 0, stream>>>(ws, sl, 1);
  row_pass <<<Bn*Zn/4, 256, 0, stream>>>(K, ws, OFF_W, 2);

  final_kernel<<<(Bn*(size_t)ZSn/4)/256, 256, 0, stream>>>(K, ws, sl);
}

// Round 2
// 1477.589 us; speedup vs baseline: 1.0930x; 1.0930x over previous
//
#include <hip/hip_runtime.h>
#include <math.h>

#define Bn 64
#define Sn 512
#define Zn 1024
#define H1n 512
#define H2n 256
#define ZSn (Zn*Sn)

// workspace float offsets
#define OFF_LP1  0          // 1024
#define OFF_VT   1024       // 256*64  (V transposed [h][b])
#define OFF_V    17408      // 64*512
#define OFF_W    50176      // 64*512
#define OFF_R    82944      // 64*1024
#define OFF_PM   148480     // 64*16*512
#define OFF_PS   672768     // 64*16*512
#define OFF_KB   1310720    // bf16 K (as ushort), 33.5M elems = 64 MB
#define NEED_BF16_BYTES ((size_t)OFF_KB*4 + (size_t)Bn*ZSn*2)

#define NINF (-__builtin_inff())

__device__ __forceinline__ float wred_max(float x){
#pragma unroll
  for (int o=32;o;o>>=1) x = fmaxf(x, __shfl_xor(x, o, 64));
  return x;
}
__device__ __forceinline__ float wred_sum(float x){
#pragma unroll
  for (int o=32;o;o>>=1) x += __shfl_xor(x, o, 64);
  return x;
}
__device__ __forceinline__ float lae(float a, float c){
  float m = fmaxf(a,c), n = fminf(a,c);
  return m + log1pf(__expf(n-m));
}
__device__ __forceinline__ float toF(float v){ return v; }
__device__ __forceinline__ float toF(unsigned short v){ return __uint_as_float(((unsigned int)v)<<16); }
__device__ __forceinline__ unsigned int pack2(float a, float b){
  unsigned int ua = __float_as_uint(a), ub = __float_as_uint(b);
  ua = (ua + 0x7fffu + ((ua>>16)&1u)) >> 16;
  ub = (ub + 0x7fffu + ((ub>>16)&1u)) & 0xffff0000u;
  return ua | ub;
}

// single block: lp1 = log_softmax(prior)
__global__ __launch_bounds__(512) void prep_kernel(const float* __restrict__ prior,
                                                   float* __restrict__ ws){
  __shared__ float red[8];
  int t = threadIdx.x;
  float x0 = prior[t], x1 = prior[t+512];
  float m = wred_max(fmaxf(x0,x1));
  if ((t&63)==0) red[t>>6] = m;
  __syncthreads();
  float M = red[0];
#pragma unroll
  for (int i=1;i<8;i++) M = fmaxf(M, red[i]);
  float e = __expf(x0-M)+__expf(x1-M);
  e = wred_sum(e);
  __syncthreads();
  if ((t&63)==0) red[t>>6] = e;
  __syncthreads();
  float T = 0.f;
#pragma unroll
  for (int i=0;i<8;i++) T += red[i];
  float lse = M + logf(T);
  ws[OFF_LP1 + t]       = x0 - lse;
  ws[OFF_LP1 + t + 512] = x1 - lse;
}

// one block per batch: softmax -> sigmoid MLP -> VT[h][b]
__global__ __launch_bounds__(512) void mlp_kernel(const float* __restrict__ sl,
    const float* __restrict__ W1, const float* __restrict__ b1,
    const float* __restrict__ W2, const float* __restrict__ b2,
    float* __restrict__ ws){
  __shared__ float p[Sn];
  __shared__ float h1s[H1n];
  __shared__ float red[8];
  int b = blockIdx.x, t = threadIdx.x;
  float x = sl[b*Sn + t];
  float m = wred_max(x);
  if ((t&63)==0) red[t>>6] = m;
  __syncthreads();
  float M = red[0];
#pragma unroll
  for (int i=1;i<8;i++) M = fmaxf(M, red[i]);
  float e = __expf(x-M);
  float es = wred_sum(e);
  __syncthreads();
  if ((t&63)==0) red[t>>6] = es;
  __syncthreads();
  float T = 0.f;
#pragma unroll
  for (int i=0;i<8;i++) T += red[i];
  p[t] = e / T;
  __syncthreads();
  float acc = b1[t];
#pragma unroll 8
  for (int s=0;s<Sn;s++) acc = fmaf(p[s], W1[s*H1n + t], acc);
  h1s[t] = 1.f/(1.f+__expf(-acc));
  __syncthreads();
  if (t < H2n){
    float a2 = b2[t];
#pragma unroll 8
    for (int s=0;s<H1n;s++) a2 = fmaf(h1s[s], W2[s*H2n + t], a2);
    ws[OFF_VT + t*Bn + b] = 1.f/(1.f+__expf(-a2));
  }
}

// K[b,zs] = sum_h VT[h][b]*Wout[h,zs] + bout[zs]
// BF=1: write packed bf16 to Kb; BF=0: write f32 to Kf.
template<int BF>
__global__ __launch_bounds__(256,1) void gemm_kernel(const float* __restrict__ Wout,
    const float* __restrict__ bout, const float* __restrict__ ws,
    float* __restrict__ Kf, unsigned int* __restrict__ Kb){
  int zh = blockIdx.x*256 + threadIdx.x;     // float2 index into zs
  const float* __restrict__ VT = ws + OFF_VT;
  float2 acc[Bn];
#pragma unroll
  for (int b=0;b<Bn;b++){ acc[b].x = 0.f; acc[b].y = 0.f; }
  const float2* Wp = (const float2*)Wout;
#pragma unroll 2
  for (int h=0; h<H2n; h++){
    float2 wv = Wp[(size_t)h*(ZSn/2) + zh];
    const float* vh = VT + (h<<6);
#pragma unroll
    for (int b=0;b<Bn;b++){
      acc[b].x = fmaf(vh[b], wv.x, acc[b].x);
      acc[b].y = fmaf(vh[b], wv.y, acc[b].y);
    }
  }
  float2 bb = ((const float2*)bout)[zh];
#pragma unroll
  for (int b=0;b<Bn;b++){
    float ax = acc[b].x + bb.x, ay = acc[b].y + bb.y;
    if (BF){
      Kb[(size_t)b*(ZSn/2) + zh] = pack2(ax, ay);
    } else {
      float2 o; o.x = ax; o.y = ay;
      ((float2*)Kf)[(size_t)b*(ZSn/2) + zh] = o;
    }
  }
}

// Fused sinkhorn iteration: block = (batch b, 64-row chunk c).
// phase0: v = (iter==0) ? 0 : lp2 - LSE_z(partials)       [also save v if mode==1]
// phase1: stage K chunk -> LDS
// phase2: per row L=LSE_s(K+v); u=lp1-L  [store r=L if mode==1]
// phase3: col partials (m,sum) of LSE_z(K+u) for this chunk -> ws
template<typename KT>
__global__ __launch_bounds__(512) void iter_fused(const KT* __restrict__ Kg,
    float* __restrict__ ws, const float* __restrict__ sl, int iter, int mode){
  __shared__ KT Ksh[64*512];
  __shared__ float vsh[512];
  __shared__ float ush[64];
  __shared__ float lsh[64];
  int t = threadIdx.x;
  int b = blockIdx.x >> 4, c = blockIdx.x & 15;
  // stage chunk (contiguous rows) into LDS
  const float4* s4 = (const float4*)(Kg + ((size_t)((b<<10) + (c<<6)) << 9));
  float4* d4 = (float4*)Ksh;
  constexpr int NV = (int)sizeof(KT)*4;   // float4s per thread: bf16->8, f32->16
#pragma unroll
  for (int i=0;i<NV;i++) d4[i*512 + t] = s4[i*512 + t];
  if (t < 64) lsh[t] = ws[OFF_LP1 + (c<<6) + t];
  // v for column s = t
  float v_s;
  if (iter == 0) v_s = 0.f;
  else {
    float M = NINF, S = 0.f;
#pragma unroll
    for (int cc=0; cc<16; cc++){
      float m = ws[OFF_PM + ((b*16+cc)<<9) + t];
      float p = ws[OFF_PS + ((b*16+cc)<<9) + t];
      float nm = fmaxf(M, m);
      S = S*__expf(M-nm) + p*__expf(m-nm);
      M = nm;
    }
    v_s = sl[(b<<9) + t] - (M + logf(S));
  }
  vsh[t] = v_s;
  if (mode) ws[OFF_V + (b<<9) + t] = v_s;   // duplicate identical writes across chunks: benign
  __syncthreads();
  // row phase: 8 waves x 8 rows
  int l = t & 63, w = t >> 6;
#pragma unroll
  for (int rr=0; rr<8; rr++){
    int row = (w<<3) + rr;
    float x[8];
    float m = NINF;
#pragma unroll
    for (int j=0;j<8;j++){
      x[j] = toF(Ksh[(row<<9) + (j<<6) + l]) + vsh[(j<<6)+l];
      m = fmaxf(m, x[j]);
    }
    m = wred_max(m);
    float s = 0.f;
#pragma unroll
    for (int j=0;j<8;j++) s += __expf(x[j]-m);
    s = wred_sum(s);
    float L = m + logf(s);
    if (l == 0){
      ush[row] = lsh[row] - L;
      if (mode) ws[OFF_R + (b<<10) + (c<<6) + row] = L;
    }
  }
  __syncthreads();
  // col phase: thread t = column s, online LSE over 64 rows
  float M = NINF, S = 0.f;
#pragma unroll 8
  for (int i=0;i<64;i++){
    float x2 = toF(Ksh[(i<<9) + t]) + ush[i];
    float nm = fmaxf(M, x2);
    S = S*__expf(M-nm) + __expf(x2-nm);
    M = nm;
  }
  ws[OFF_PM + ((b*16+c)<<9) + t] = M;
  ws[OFF_PS + ((b*16+c)<<9) + t] = S;
}

// combine partials -> L_col; accept_raw = lp2 - v - L_col; w = v + accept_raw - max
__global__ __launch_bounds__(512) void wker(float* __restrict__ ws, const float* __restrict__ sl){
  __shared__ float red[8];
  int b = blockIdx.x, s = threadIdx.x;
  float M = NINF, S = 0.f;
#pragma unroll
  for (int cc=0; cc<16; cc++){
    float m = ws[OFF_PM + ((b*16+cc)<<9) + s];
    float p = ws[OFF_PS + ((b*16+cc)<<9) + s];
    float nm = fmaxf(M, m);
    S = S*__expf(M-nm) + p*__expf(m-nm);
    M = nm;
  }
  float L = M + logf(S);
  float v = ws[OFF_V + (b<<9) + s];
  float araw = sl[(b<<9)+s] - v - L;
  float mm = wred_max(araw);
  if ((s&63)==0) red[s>>6] = mm;
  __syncthreads();
  float amax = red[0];
#pragma unroll
  for (int i=1;i<8;i++) amax = fmaxf(amax, red[i]);
  ws[OFF_W + (b<<9) + s] = v + araw - amax;
}

// fused resample + output: wave per row, all in registers.
// a = K - r + w; lk = LSE_s(a); rs = lk>=0 ? -inf : log1p(-exp(lk))
// out = lp1[z] + logaddexp(a, rs + lp2)
template<typename KT>
__global__ __launch_bounds__(512) void final_fused(const KT* Kg,
    float* out, const float* __restrict__ ws, const float* __restrict__ sl){
  int t = threadIdx.x, l = t & 63, wv = t >> 6;
  int row = blockIdx.x*8 + wv;
  int b = row >> 10, z = row & (Zn-1);
  const KT* Kr = Kg + ((size_t)row << 9);
  const float* wr = ws + OFF_W + (b << 9);
  const float* pr = sl + (b << 9);
  float r  = ws[OFF_R + row];
  float l1 = ws[OFF_LP1 + z];
  float k[8], a[8];
  float m = NINF;
#pragma unroll
  for (int j=0;j<8;j++){
    k[j] = toF(Kr[(j<<6)+l]);
    a[j] = k[j] - r + wr[(j<<6)+l];
    m = fmaxf(m, a[j]);
  }
  m = wred_max(m);
  float s = 0.f;
#pragma unroll
  for (int j=0;j<8;j++) s += __expf(a[j]-m);
  s = wred_sum(s);
  float lk = m + logf(s);           // = LSE_s(K+w) - r  (a already has -r)
  float rs = (lk >= 0.f) ? NINF : log1pf(-__expf(lk));
  float* Or = out + ((size_t)row << 9);
#pragma unroll
  for (int j=0;j<8;j++){
    Or[(j<<6)+l] = l1 + lae(a[j], rs + pr[(j<<6)+l]);
  }
}

extern "C" void kernel_launch(void* const* d_in, const int* in_sizes, int n_in,
                              void* d_out, int out_size, void* d_ws, size_t ws_size,
                              hipStream_t stream) {
  const float* sl    = (const float*)d_in[0];
  const float* W1    = (const float*)d_in[1];
  const float* b1    = (const float*)d_in[2];
  const float* W2    = (const float*)d_in[3];
  const float* b2    = (const float*)d_in[4];
  const float* Wout  = (const float*)d_in[5];
  const float* bout  = (const float*)d_in[6];
  const float* prior = (const float*)d_in[7];
  float* ws = (float*)d_ws;
  float* Kf = (float*)d_out;
  unsigned short* Kb = (unsigned short*)(ws + OFF_KB);
  const bool use_bf16 = (ws_size >= NEED_BF16_BYTES);

  prep_kernel<<<1, 512, 0, stream>>>(prior, ws);
  mlp_kernel<<<Bn, 512, 0, stream>>>(sl, W1, b1, W2, b2, ws);

  if (use_bf16){
    gemm_kernel<1><<<ZSn/512, 256, 0, stream>>>(Wout, bout, ws, nullptr, (unsigned int*)Kb);
    for (int it = 0; it < 10; ++it)
      iter_fused<unsigned short><<<Bn*16, 512, 0, stream>>>(Kb, ws, sl, it, 0);
    iter_fused<unsigned short><<<Bn*16, 512, 0, stream>>>(Kb, ws, sl, 10, 1);
    wker<<<Bn, 512, 0, stream>>>(ws, sl);
    final_fused<unsigned short><<<Bn*Zn/8, 512, 0, stream>>>(Kb, (float*)d_out, ws, sl);
  } else {
    gemm_kernel<0><<<ZSn/512, 256, 0, stream>>>(Wout, bout, ws, Kf, nullptr);
    for (int it = 0; it < 10; ++it)
      iter_fused<float><<<Bn*16, 512, 0, stream>>>(Kf, ws, sl, it, 0);
    iter_fused<float><<<Bn*16, 512, 0, stream>>>(Kf, ws, sl, 10, 1);
    wker<<<Bn, 512, 0, stream>>>(ws, sl);
    final_fused<float><<<Bn*Zn/8, 512, 0, stream>>>(Kf, (float*)d_out, ws, sl);
  }
}